// Round 6
// baseline (4598.129 us; speedup 1.0000x reference)
//
#include <hip/hip_runtime.h>

#define Tn 64
#define Bn 512
#define Dn 512
#define Hn 2048
#define CH 16   // batch chunks, M=32 rows each
#define SL 16   // H slices, 128 cols each

typedef __attribute__((ext_vector_type(8))) short s16x8;
typedef __attribute__((ext_vector_type(4))) float f32x4;
typedef __attribute__((ext_vector_type(4))) unsigned int u32x4;
typedef unsigned int u32;
typedef unsigned long long u64;
typedef unsigned short u16;

__device__ __forceinline__ u16 f2bf(float f) {
    u32 u = __builtin_bit_cast(u32, f);
    return (u16)((u + 0x7fffu + ((u >> 16) & 1u)) >> 16);
}
__device__ __forceinline__ float bf2f(u32 v) {
    return __builtin_bit_cast(float, v << 16);
}
__device__ __forceinline__ float tanh_fast(float x) {
    float e = __builtin_amdgcn_exp2f(x * 2.885390081777927f);
    return 1.0f - 2.0f * __builtin_amdgcn_rcpf(e + 1.0f);
}
__device__ __forceinline__ u32 agent_ld(const u32* p) {
    return __hip_atomic_load((u32*)p, __ATOMIC_RELAXED, __HIP_MEMORY_SCOPE_AGENT);
}
__device__ __forceinline__ void agent_st(u32* p, u32 v) {
    __hip_atomic_store(p, v, __ATOMIC_RELAXED, __HIP_MEMORY_SCOPE_AGENT);
}

// Pack W1 (512x2048) and W2 (2048x512), f32 row-major -> bf16 MFMA-B-fragment order.
__global__ void pack_w(const float* __restrict__ W1, const float* __restrict__ W2,
                       u16* __restrict__ w1p, u16* __restrict__ w2p) {
    const int i = blockIdx.x * 256 + threadIdx.x;
    const int e = i & 7;
    const int lane = (i >> 3) & 63;
    const int krem = ((lane >> 4) << 3) + e;
    const int ncol = lane & 15;
    {   // W1: K=512 (16 ktiles), N=2048 (128 ntiles)
        const int kt = (i >> 9) & 15, nt = i >> 13;
        const int k = (kt << 5) + krem, n = (nt << 4) + ncol;
        w1p[i] = f2bf(W1[k * Hn + n]);
    }
    {   // W2: K=2048 (64 ktiles), N=512 (32 ntiles)
        const int kt = (i >> 9) & 63, nt = i >> 15;
        const int k = (kt << 5) + krem, n = (nt << 4) + ncol;
        w2p[i] = f2bf(W2[k * Dn + n]);
    }
}

// 256 WGs = 16 chunks x 16 slices. bid = r*16 + h.
// v6: exchange stores sc0 sc1 (MALL write-back, no HBM write-through);
// flag-gated INCREMENTAL gather on both rendezvous (overlap detect with loads).
__launch_bounds__(512, 2)
__global__ void ode_v6(const float* __restrict__ y0, const float* __restrict__ tt,
                       const float* __restrict__ b1, const float* __restrict__ b2,
                       const u16* __restrict__ w1p, const u16* __restrict__ w2p,
                       float* __restrict__ out, u16* __restrict__ ybuf,
                       u16* __restrict__ kpart, u32* __restrict__ flags1,
                       u32* __restrict__ flags2) {
    __shared__ u16 lds_A[32 * 512];    // 32KB, row stride 1024B, xor-swz ((row&7)<<4)
    __shared__ u16 lds_H[32 * 128];    // 8KB,  row stride 256B,  xor-swz ((row&7)<<4)
    char* ldsAb = (char*)lds_A;
    char* ldsHb = (char*)lds_H;

    const int tid = threadIdx.x;
    const int w = tid >> 6, lane = tid & 63, l15 = lane & 15, kg = lane >> 4;
    const int bid = blockIdx.x;
    const int r = bid >> 4, h = bid & 15;

    // owner/reducer mapping: col sc in slice, rowpair rp
    const int sc = tid >> 4;                 // 0..31
    const int rp = tid & 15;                 // 0..15
    const int colg = (h << 5) + sc;
    const int brow0 = (r << 5) + 2 * rp, brow1 = brow0 + 1;
    const float b2c = b2[colg];
    float ys0 = y0[brow0 * Dn + colg];
    float ys1 = y0[brow1 * Dn + colg];
    __builtin_nontemporal_store(ys0, &out[brow0 * Dn + colg]);
    __builtin_nontemporal_store(ys1, &out[brow1 * Dn + colg]);
    float ks0 = 0.f, ks1 = 0.f, dt0 = 0.f, dt1 = 0.f;

    // GEMM wave constants
    const int mt = w & 1;
    const int np = w >> 1;
    const float bia0 = b1[(h << 7) + ((np << 1) << 4) + l15];
    const float bia1 = b1[(h << 7) + (((np << 1) + 1) << 4) + l15];
    const u16* wp1 = w1p + ((size_t)((h << 3) + (np << 1)) << 4) * 512 + (lane << 3);
    const u16* wp2 = w2p + ((size_t)(np << 3) * 64 + (h << 2)) * 512 + (lane << 3);

    const u32 arow = (u32)((mt << 4) + l15);
    const u32 abase = arow * 1024u + ((u32)kg << 4);
    const u32 aswz = (arow & 7u) << 4;
    const u32 hbase = arow * 256u + ((u32)kg << 4);
    const u32 hswz = aswz;

    u32* ybr = (u32*)(ybuf + (size_t)r * 32 * 512);
    const u32* kown = (const u32*)((const char*)kpart + (size_t)(((r << 4) + h) << 4) * 2048);
    char* kprod = (char*)kpart + (size_t)(r << 8) * 2048;   // + (o*16+h)*2048
    u32* fl1p = flags1 + (r << 6);   // 16 packed dwords, one 64B line per chunk
    u32* fl2p = flags2 + (r << 6);

    // stage-A stager mapping (per wave, 2 stripes): lane -> (row, 32B-half)
    const u32 st_row = (u32)(lane >> 1);
    const u32 st_half = (u32)(lane & 1);

    #pragma unroll 1
    for (int s = 0; s < 252; ++s) {
        // ================= stage A: yin -> lds_A =================
        if (s == 0) {
            const float4* y0c = (const float4*)(y0 + (size_t)(r << 5) * Dn);
            #pragma unroll
            for (int it = 0; it < 8; ++it) {
                const int idx = (it << 9) + tid;          // over [32 rows][128 f4]
                const float4 v = y0c[idx];
                const u32 row = (u32)idx >> 7;
                u64 pk = (u64)((u32)f2bf(v.x) | ((u32)f2bf(v.y) << 16)) |
                         ((u64)((u32)f2bf(v.z) | ((u32)f2bf(v.w) << 16)) << 32);
                const u32 dst = (row * 1024u + ((u32)(idx & 127) << 3)) ^ ((row & 7u) << 4);
                *(u64*)(ldsAb + dst) = pk;
            }
        } else {
            // wave w stages stripes ho = w and w+8, each gated on flag2[ho]
            const u32 tgt2 = (u32)s;
            #pragma unroll
            for (int q = 0; q < 2; ++q) {
                const int ho = w + (q << 3);
                while (agent_ld(fl2p + ho) < tgt2) __builtin_amdgcn_s_sleep(1);
                const u32 src = st_row * 1024u + ((u32)ho << 6) + (st_half << 5);
                u32x4 d0, d1;
                asm volatile("global_load_dwordx4 %0, %1, %2 sc0 sc1 nt"
                             : "=v"(d0) : "v"(src), "s"(ybr) : "memory");
                asm volatile("global_load_dwordx4 %0, %1, %2 sc0 sc1 nt"
                             : "=v"(d1) : "v"(src + 16u), "s"(ybr) : "memory");
                asm volatile("s_waitcnt vmcnt(0)"
                             : "+v"(d0), "+v"(d1) :: "memory");
                const u32 dst = src ^ ((st_row & 7u) << 4);
                *(u32x4*)(ldsAb + dst) = d0;
                *(u32x4*)(ldsAb + (dst ^ 16u)) = d1;
            }
        }
        __syncthreads();

        // ================= GEMM1: hid = tanh(A @ W1slice + b1) =================
        f32x4 a1[2];
        a1[0] = f32x4{bia0, bia0, bia0, bia0};
        a1[1] = f32x4{bia1, bia1, bia1, bia1};
        #pragma unroll
        for (int kt = 0; kt < 16; ++kt) {
            const s16x8 a = *(const s16x8*)(ldsAb + ((abase + ((u32)kt << 6)) ^ aswz));
            const s16x8 b0 = *(const s16x8*)(wp1 + ((size_t)kt << 9));
            const s16x8 b1f = *(const s16x8*)(wp1 + ((size_t)(16 + kt) << 9));
            a1[0] = __builtin_amdgcn_mfma_f32_16x16x32_bf16(a, b0, a1[0], 0, 0, 0);
            a1[1] = __builtin_amdgcn_mfma_f32_16x16x32_bf16(a, b1f, a1[1], 0, 0, 0);
        }
        #pragma unroll
        for (int n = 0; n < 2; ++n) {
            #pragma unroll
            for (int j = 0; j < 4; ++j) {
                const u32 row = (u32)((mt << 4) + (kg << 2) + j);
                const u32 col = (u32)((((np << 1) + n) << 4) + l15);
                const u32 bo = (row * 256u + (col << 1)) ^ ((row & 7u) << 4);
                *(u16*)(ldsHb + bo) = f2bf(tanh_fast(a1[n][j]));
            }
        }
        __syncthreads();

        // ================= GEMM2: partial = hid @ W2slice (K=128) =================
        f32x4 acc[8];
        #pragma unroll
        for (int c = 0; c < 8; ++c) acc[c] = f32x4{0.f, 0.f, 0.f, 0.f};
        #pragma unroll
        for (int ks = 0; ks < 4; ++ks) {
            const s16x8 ha = *(const s16x8*)(ldsHb + ((hbase + ((u32)ks << 6)) ^ hswz));
            #pragma unroll
            for (int c = 0; c < 8; ++c) {
                const s16x8 bf = *(const s16x8*)(wp2 + ((size_t)((c << 6) + ks) << 9));
                acc[c] = __builtin_amdgcn_mfma_f32_16x16x32_bf16(ha, bf, acc[c], 0, 0, 0);
            }
        }
        // sc0 sc1 stores into owner-contiguous col-major stripes (r, o=nt>>1, h)
        #pragma unroll
        for (int c = 0; c < 8; ++c) {
            const int nt = (np << 3) + c;
            const int o = nt >> 1;
            const int sc2 = ((nt & 1) << 4) + l15;
            const u32 off = (u32)((sc2 << 6) + (mt << 5) + (kg << 3));
            u64 pk = (u64)((u32)f2bf(acc[c][0]) | ((u32)f2bf(acc[c][1]) << 16)) |
                     ((u64)((u32)f2bf(acc[c][2]) | ((u32)f2bf(acc[c][3]) << 16)) << 32);
            void* pa = kprod + (size_t)((o << 4) + h) * 2048 + off;
            asm volatile("global_store_dwordx2 %0, %1, off sc0 sc1"
                         :: "v"(pa), "v"(pk) : "memory");
        }
        asm volatile("s_waitcnt vmcnt(0)" ::: "memory");
        __syncthreads();                      // all partials globally visible
        if (tid == 0) agent_st(fl1p + h, (u32)(s + 1));

        // ===== owner reduce: flag-gated incremental gather of 16 stripes =====
        float s0 = 0.f, s1 = 0.f;
        {
            const u32 vo2 = (u32)(tid << 2);
            const u32 tgt = (u32)(s + 1);
            u32 t0, t1, t2, t3, t4, t5, t6, t7;
#define WFLAG(P) while (agent_ld(fl1p + (P)) < tgt) __builtin_amdgcn_s_sleep(1)
#define NT_LD(dst, P) asm volatile("global_load_dword %0, %1, %2 sc0 sc1 nt" \
        : "=v"(dst) : "v"(vo2 + ((u32)(P) << 11)), "s"(kown) : "memory")
#define ACC8() do { \
        s0 += bf2f(t0 & 0xffffu); s1 += bf2f(t0 >> 16); \
        s0 += bf2f(t1 & 0xffffu); s1 += bf2f(t1 >> 16); \
        s0 += bf2f(t2 & 0xffffu); s1 += bf2f(t2 >> 16); \
        s0 += bf2f(t3 & 0xffffu); s1 += bf2f(t3 >> 16); \
        s0 += bf2f(t4 & 0xffffu); s1 += bf2f(t4 >> 16); \
        s0 += bf2f(t5 & 0xffffu); s1 += bf2f(t5 >> 16); \
        s0 += bf2f(t6 & 0xffffu); s1 += bf2f(t6 >> 16); \
        s0 += bf2f(t7 & 0xffffu); s1 += bf2f(t7 >> 16); } while (0)
            WFLAG(0); NT_LD(t0, 0);  WFLAG(1); NT_LD(t1, 1);
            WFLAG(2); NT_LD(t2, 2);  WFLAG(3); NT_LD(t3, 3);
            WFLAG(4); NT_LD(t4, 4);  WFLAG(5); NT_LD(t5, 5);
            WFLAG(6); NT_LD(t6, 6);  WFLAG(7); NT_LD(t7, 7);
            asm volatile("s_waitcnt vmcnt(0)"
                         : "+v"(t0), "+v"(t1), "+v"(t2), "+v"(t3),
                           "+v"(t4), "+v"(t5), "+v"(t6), "+v"(t7) :: "memory");
            ACC8();
            WFLAG(8); NT_LD(t0, 8);   WFLAG(9); NT_LD(t1, 9);
            WFLAG(10); NT_LD(t2, 10); WFLAG(11); NT_LD(t3, 11);
            WFLAG(12); NT_LD(t4, 12); WFLAG(13); NT_LD(t5, 13);
            WFLAG(14); NT_LD(t6, 14); WFLAG(15); NT_LD(t7, 15);
            asm volatile("s_waitcnt vmcnt(0)"
                         : "+v"(t0), "+v"(t1), "+v"(t2), "+v"(t3),
                           "+v"(t4), "+v"(t5), "+v"(t6), "+v"(t7) :: "memory");
            ACC8();
#undef WFLAG
#undef NT_LD
#undef ACC8
        }
        const int step = s >> 2, sub = s & 3;
        if (sub == 0) {
            dt0 = tt[(step + 1) * Bn + brow0] - tt[step * Bn + brow0];
            dt1 = tt[(step + 1) * Bn + brow1] - tt[step * Bn + brow1];
        }
        const float k0 = dt0 * (s0 + b2c), k1 = dt1 * (s1 + b2c);
        float yin0, yin1;
        if (sub == 0)      { ks0 = k0;        ks1 = k1;        yin0 = ys0 + 0.5f * k0; yin1 = ys1 + 0.5f * k1; }
        else if (sub == 1) { ks0 += 2.f * k0; ks1 += 2.f * k1; yin0 = ys0 + 0.5f * k0; yin1 = ys1 + 0.5f * k1; }
        else if (sub == 2) { ks0 += 2.f * k0; ks1 += 2.f * k1; yin0 = ys0 + k0;        yin1 = ys1 + k1; }
        else {
            ks0 += k0; ks1 += k1;
            ys0 += ks0 * (1.f / 6.f); ys1 += ks1 * (1.f / 6.f);
            yin0 = ys0; yin1 = ys1;
            __builtin_nontemporal_store(ys0, &out[((step + 1) * Bn + brow0) * Dn + colg]);
            __builtin_nontemporal_store(ys1, &out[((step + 1) * Bn + brow1) * Dn + colg]);
        }
        if (s < 251) {
            // broadcast next yin: row-major [32][512] bf16, u32 = col-pair
            const u32 my = (u32)f2bf(yin0) | ((u32)f2bf(yin1) << 16);
            const u32 pu = (u32)__shfl_xor((int)my, 16, 64);
            u32 word; int rowsel;
            if ((sc & 1) == 0) { word = (my & 0xffffu) | (pu << 16);       rowsel = 2 * rp; }
            else               { word = (pu >> 16) | (my & 0xffff0000u);   rowsel = 2 * rp + 1; }
            u32* baddr = ybr + (rowsel << 8) + (colg >> 1);
            asm volatile("global_store_dword %0, %1, off sc0 sc1"
                         :: "v"(baddr), "v"(word) : "memory");
            asm volatile("s_waitcnt vmcnt(0)" ::: "memory");
            __syncthreads();
            if (tid == 0) agent_st(fl2p + h, (u32)(s + 1));
        }
    }
}

// ---------------- fallback: round-1 kernel (32 WGs) ----------------
__launch_bounds__(512, 2)
__global__ void ode_rk4_fb(const float* __restrict__ y0, const float* __restrict__ tt,
                           const float* __restrict__ b1, const float* __restrict__ b2,
                           const u16* __restrict__ w1p, const u16* __restrict__ w2p,
                           float* __restrict__ out) {
    __shared__ u16 lds_ys[16 * Dn];
    __shared__ u16 lds_hid[16 * Hn];
    __shared__ float lds_dt[16];
    const int tid = threadIdx.x;
    const int w = tid >> 6, lane = tid & 63, l15 = lane & 15, kgrp = lane >> 4;
    const int row0 = blockIdx.x << 4;
    float yreg[4][4], ksum[4][4], kk[4][4];
    float b1v[16], b2v[4], dtv[4];
    #pragma unroll
    for (int nt = 0; nt < 16; ++nt) b1v[nt] = b1[(w << 8) + (nt << 4) + l15];
    #pragma unroll
    for (int c = 0; c < 4; ++c) b2v[c] = b2[(w << 6) + (c << 4) + l15];
    #pragma unroll
    for (int c = 0; c < 4; ++c)
        #pragma unroll
        for (int j = 0; j < 4; ++j) {
            const int rr = (kgrp << 2) + j;
            const int col = (w << 6) + (c << 4) + l15;
            const float v = y0[(row0 + rr) * Dn + col];
            yreg[c][j] = v; ksum[c][j] = 0.f; kk[c][j] = 0.f;
            out[(row0 + rr) * Dn + col] = v;
        }
    const u16* wv1 = w1p + ((w << 4) * (16 * 512)) + (lane << 3);
    const u16* wv2 = w2p + ((w << 2) * (64 * 512)) + (lane << 3);
    const int arow = l15;
    const unsigned swzA = (unsigned)((arow & 7) << 3);
    for (int step = 0; step < Tn - 1; ++step) {
        if (tid < 16)
            lds_dt[tid] = tt[(step + 1) * Bn + row0 + tid] - tt[step * Bn + row0 + tid];
        #pragma unroll 1
        for (int s = 0; s < 4; ++s) {
            const float ci = (s == 3) ? 1.0f : ((s == 0) ? 0.0f : 0.5f);
            #pragma unroll
            for (int c = 0; c < 4; ++c)
                #pragma unroll
                for (int j = 0; j < 4; ++j) {
                    const int rr = (kgrp << 2) + j;
                    const int col = (w << 6) + (c << 4) + l15;
                    lds_ys[(unsigned)((rr << 9) + col) ^ (unsigned)((rr & 7) << 3)] =
                        f2bf(yreg[c][j] + ci * kk[c][j]);
                }
            __syncthreads();
            if (s == 0) {
                #pragma unroll
                for (int j = 0; j < 4; ++j) dtv[j] = lds_dt[(kgrp << 2) + j];
            }
            f32x4 acc[16];
            #pragma unroll
            for (int nt = 0; nt < 16; ++nt)
                #pragma unroll
                for (int j = 0; j < 4; ++j) acc[nt][j] = b1v[nt];
            #pragma unroll 2
            for (int kt = 0; kt < 16; ++kt) {
                const unsigned ia = ((unsigned)((arow << 9) + (kt << 5) + (kgrp << 3))) ^ swzA;
                const s16x8 a = *(const s16x8*)&lds_ys[ia];
                #pragma unroll
                for (int nt = 0; nt < 16; ++nt) {
                    const s16x8 bfrag = *(const s16x8*)&wv1[nt * 8192 + kt * 512];
                    acc[nt] = __builtin_amdgcn_mfma_f32_16x16x32_bf16(a, bfrag, acc[nt], 0, 0, 0);
                }
            }
            #pragma unroll
            for (int nt = 0; nt < 16; ++nt)
                #pragma unroll
                for (int j = 0; j < 4; ++j) {
                    const int rr = (kgrp << 2) + j;
                    const int col = (w << 8) + (nt << 4) + l15;
                    lds_hid[(unsigned)((rr << 11) + col) ^ (unsigned)((rr & 7) << 3)] =
                        f2bf(tanh_fast(acc[nt][j]));
                }
            __syncthreads();
            f32x4 acc2[4];
            #pragma unroll
            for (int c = 0; c < 4; ++c)
                #pragma unroll
                for (int j = 0; j < 4; ++j) acc2[c][j] = 0.f;
            #pragma unroll 2
            for (int kt = 0; kt < 64; ++kt) {
                const unsigned ia = ((unsigned)((arow << 11) + (kt << 5) + (kgrp << 3))) ^ swzA;
                const s16x8 a = *(const s16x8*)&lds_hid[ia];
                #pragma unroll
                for (int c = 0; c < 4; ++c) {
                    const s16x8 bfrag = *(const s16x8*)&wv2[c * 32768 + kt * 512];
                    acc2[c] = __builtin_amdgcn_mfma_f32_16x16x32_bf16(a, bfrag, acc2[c], 0, 0, 0);
                }
            }
            const float wq = (s == 0 || s == 3) ? 1.0f : 2.0f;
            #pragma unroll
            for (int c = 0; c < 4; ++c)
                #pragma unroll
                for (int j = 0; j < 4; ++j) {
                    const float kv = dtv[j] * (acc2[c][j] + b2v[c]);
                    kk[c][j] = kv;
                    ksum[c][j] = (s == 0) ? kv : ksum[c][j] + wq * kv;
                }
        }
        #pragma unroll
        for (int c = 0; c < 4; ++c)
            #pragma unroll
            for (int j = 0; j < 4; ++j) {
                const int rr = (kgrp << 2) + j;
                const int col = (w << 6) + (c << 4) + l15;
                yreg[c][j] += ksum[c][j] * (1.0f / 6.0f);
                out[((step + 1) * Bn + row0 + rr) * Dn + col] = yreg[c][j];
            }
    }
}

extern "C" void kernel_launch(void* const* d_in, const int* in_sizes, int n_in,
                              void* d_out, int out_size, void* d_ws, size_t ws_size,
                              hipStream_t stream) {
    const float* y0 = (const float*)d_in[0];
    const float* tt = (const float*)d_in[1];
    const float* W1 = (const float*)d_in[2];
    const float* b1 = (const float*)d_in[3];
    const float* W2 = (const float*)d_in[4];
    const float* b2 = (const float*)d_in[5];
    float* out = (float*)d_out;
    char* ws = (char*)d_ws;

    const size_t sz_fl = (size_t)256 * 256;                 // flag arrays (16 chunks x 256B)
    const size_t sz_w = (size_t)Dn * Hn * 2;                // 2MB each
    const size_t sz_ybuf = (size_t)CH * 32 * 512 * 2;       // 512KB
    const size_t sz_kpart = (size_t)CH * 16 * 16 * 2048;    // 8MB
    const size_t needed = 2 * sz_fl + 2 * sz_w + sz_ybuf + sz_kpart + 4096;

    u32* flags1 = (u32*)ws;
    u32* flags2 = (u32*)(ws + sz_fl);
    u16* w1p = (u16*)(ws + 2 * sz_fl);
    u16* w2p = (u16*)(ws + 2 * sz_fl + sz_w);
    u16* ybuf = (u16*)(ws + 2 * sz_fl + 2 * sz_w);
    u16* kpart = (u16*)(ws + 2 * sz_fl + 2 * sz_w + sz_ybuf);

    if (ws_size >= needed) {
        hipMemsetAsync(ws, 0, 2 * sz_fl, stream);
        pack_w<<<4096, 256, 0, stream>>>(W1, W2, w1p, w2p);
        void* args[] = {&y0, &tt, &b1, &b2, &w1p, &w2p, &out, &ybuf, &kpart, &flags1, &flags2};
        hipLaunchCooperativeKernel((void*)ode_v6, dim3(256), dim3(512), args, 0, stream);
    } else {
        u16* f1 = (u16*)ws;
        u16* f2 = f1 + (size_t)Dn * Hn;
        pack_w<<<4096, 256, 0, stream>>>(W1, W2, f1, f2);
        ode_rk4_fb<<<32, 512, 0, stream>>>(y0, tt, b1, b2, f1, f2, out);
    }
}

// Round 7
// 2364.293 us; speedup vs baseline: 1.9448x; 1.9448x over previous
//
#include <hip/hip_runtime.h>

#define Tn 64
#define Bn 512
#define Dn 512
#define Hn 2048

typedef __attribute__((ext_vector_type(8))) short s16x8;
typedef __attribute__((ext_vector_type(4))) float f32x4;
typedef __attribute__((ext_vector_type(4))) unsigned int u32x4;
typedef unsigned int u32;
typedef unsigned long long u64;
typedef unsigned short u16;

__device__ __forceinline__ u16 f2bf(float f) {
    u32 u = __builtin_bit_cast(u32, f);
    return (u16)((u + 0x7fffu + ((u >> 16) & 1u)) >> 16);
}
__device__ __forceinline__ float bf2f(u32 v) {
    return __builtin_bit_cast(float, v << 16);
}
__device__ __forceinline__ float tanh_fast(float x) {
    float e = __builtin_amdgcn_exp2f(x * 2.885390081777927f);
    return 1.0f - 2.0f * __builtin_amdgcn_rcpf(e + 1.0f);
}
__device__ __forceinline__ u32 agent_ld(const u32* p) {
    return __hip_atomic_load((u32*)p, __ATOMIC_RELAXED, __HIP_MEMORY_SCOPE_AGENT);
}
__device__ __forceinline__ void agent_st(u32* p, u32 v) {
    __hip_atomic_store(p, v, __ATOMIC_RELAXED, __HIP_MEMORY_SCOPE_AGENT);
}

// Pack W1 (512x2048) and W2 (2048x512), f32 row-major -> bf16 MFMA-B-fragment order.
__global__ void pack_w(const float* __restrict__ W1, const float* __restrict__ W2,
                       u16* __restrict__ w1p, u16* __restrict__ w2p) {
    const int i = blockIdx.x * 256 + threadIdx.x;
    const int e = i & 7;
    const int lane = (i >> 3) & 63;
    const int krem = ((lane >> 4) << 3) + e;
    const int ncol = lane & 15;
    {   // W1: K=512 (16 ktiles), N=2048 (128 ntiles)
        const int kt = (i >> 9) & 15, nt = i >> 13;
        const int k = (kt << 5) + krem, n = (nt << 4) + ncol;
        w1p[i] = f2bf(W1[k * Hn + n]);
    }
    {   // W2: K=2048 (64 ktiles), N=512 (32 ntiles)
        const int kt = (i >> 9) & 63, nt = i >> 15;
        const int k = (kt << 5) + krem, n = (nt << 4) + ncol;
        w2p[i] = f2bf(W2[k * Dn + n]);
    }
}

// ---- v7 helpers (all force-inlined; static indexing preserved) ----

__device__ __forceinline__ void stage_a(const u32* ybrC, char* ldsA, int tid) {
    // ybuf chunk = [16 rows][256 u32]; thread covers bytes [tid*32, tid*32+32)
    u32x4 d0, d1;
    const u32 vo = (u32)(tid << 5);
    asm volatile("global_load_dwordx4 %0, %1, %2 sc0 sc1 nt"
                 : "=v"(d0) : "v"(vo), "s"(ybrC) : "memory");
    asm volatile("global_load_dwordx4 %0, %1, %2 sc0 sc1 nt"
                 : "=v"(d1) : "v"(vo + 16u), "s"(ybrC) : "memory");
    asm volatile("s_waitcnt vmcnt(0)" : "+v"(d0), "+v"(d1) :: "memory");
    const u32 row = (u32)(tid >> 5);
    const u32 dst = vo ^ ((row & 7u) << 4);
    *(u32x4*)(ldsA + dst) = d0;
    *(u32x4*)(ldsA + (dst ^ 16u)) = d1;
}

__device__ __forceinline__ void stage_a0(const float* y0, int c, char* ldsA, int tid) {
    const float4* yc = (const float4*)(y0 + (size_t)(c << 4) * Dn);
    #pragma unroll
    for (int it = 0; it < 4; ++it) {
        const int idx = (it << 9) + tid;            // over [16 rows][128 f4]
        const float4 v = yc[idx];
        const u32 row = (u32)idx >> 7;
        u64 pk = (u64)((u32)f2bf(v.x) | ((u32)f2bf(v.y) << 16)) |
                 ((u64)((u32)f2bf(v.z) | ((u32)f2bf(v.w) << 16)) << 32);
        const u32 dst = (row * 1024u + ((u32)(idx & 127) << 3)) ^ ((row & 7u) << 4);
        *(u64*)(ldsA + dst) = pk;
    }
}

__device__ __forceinline__ void gemm1(const char* ldsA, char* ldsH,
                                      const s16x8 (&w1r)[16], float bia,
                                      u32 abase, u32 aswz, int w, int l15, int kg) {
    f32x4 g1 = f32x4{bia, bia, bia, bia};
    #pragma unroll
    for (int kt = 0; kt < 16; ++kt) {
        const s16x8 a = *(const s16x8*)(ldsA + ((abase + ((u32)kt << 6)) ^ aswz));
        g1 = __builtin_amdgcn_mfma_f32_16x16x32_bf16(a, w1r[kt], g1, 0, 0, 0);
    }
    #pragma unroll
    for (int j = 0; j < 4; ++j) {
        const u32 row = (u32)((kg << 2) + j);
        const u32 bo = (row * 256u + (((u32)(w << 4) + (u32)l15) << 1)) ^ ((row & 7u) << 4);
        *(u16*)(ldsH + bo) = f2bf(tanh_fast(g1[j]));
    }
}

__device__ __forceinline__ void gemm2_store(const char* ldsH, char* kpC,
                                            const s16x8 (&w2r)[4][4],
                                            u32 hbase, u32 aswz, int w, int l15,
                                            int kg, int h) {
    f32x4 acc[4];
    #pragma unroll
    for (int c = 0; c < 4; ++c) acc[c] = f32x4{0.f, 0.f, 0.f, 0.f};
    #pragma unroll
    for (int ks2 = 0; ks2 < 4; ++ks2) {
        const s16x8 ha = *(const s16x8*)(ldsH + ((hbase + ((u32)ks2 << 6)) ^ aswz));
        #pragma unroll
        for (int c = 0; c < 4; ++c)
            acc[c] = __builtin_amdgcn_mfma_f32_16x16x32_bf16(ha, w2r[c][ks2], acc[c], 0, 0, 0);
    }
    // partial stripes: block (o, producer h) = [32 sc2][16 rows] bf16 col-major, 1 KB
    #pragma unroll
    for (int c = 0; c < 4; ++c) {
        const int nt = (w << 2) + c;
        const int o = nt >> 1;
        const int sc2 = ((nt & 1) << 4) + l15;
        u64 pk = (u64)((u32)f2bf(acc[c][0]) | ((u32)f2bf(acc[c][1]) << 16)) |
                 ((u64)((u32)f2bf(acc[c][2]) | ((u32)f2bf(acc[c][3]) << 16)) << 32);
        void* pa = kpC + (size_t)((o << 4) + h) * 1024 + (u32)((sc2 << 5) + (kg << 3));
        asm volatile("global_store_dwordx2 %0, %1, off sc0 sc1"
                     :: "v"(pa), "v"(pk) : "memory");
    }
}

__device__ __forceinline__ void owner_phase(int s, float& ys, float& ks, float& dtv,
                                            int brow, const char* kpC, u32* ybrC,
                                            u32* fl1C, u32* fl2C,
                                            const float* tt, float* out, float b2c,
                                            int colg, int sc, int rm, int h, int tid) {
    if (tid < 16) {
        const u32 tg = (u32)(s + 1);
        while (agent_ld(fl1C + tid) < tg) __builtin_amdgcn_s_sleep(1);
    }
    __syncthreads();
    float sacc = 0.f;
    {
        const u32 bo = ((u32)h << 14) + (u32)((sc << 5) + ((rm >> 1) << 2));
        u32 t0,t1,t2,t3,t4,t5,t6,t7,t8,t9,ta,tb,tc,td,te,tf;
#define KLD(d, P) asm volatile("global_load_dword %0, %1, %2 sc0 sc1 nt" \
        : "=v"(d) : "v"(bo + (u32)((P) << 10)), "s"(kpC) : "memory")
        KLD(t0,0); KLD(t1,1); KLD(t2,2); KLD(t3,3);
        KLD(t4,4); KLD(t5,5); KLD(t6,6); KLD(t7,7);
        KLD(t8,8); KLD(t9,9); KLD(ta,10); KLD(tb,11);
        KLD(tc,12); KLD(td,13); KLD(te,14); KLD(tf,15);
#undef KLD
        asm volatile("s_waitcnt vmcnt(0)"
                     : "+v"(t0),"+v"(t1),"+v"(t2),"+v"(t3),
                       "+v"(t4),"+v"(t5),"+v"(t6),"+v"(t7),
                       "+v"(t8),"+v"(t9),"+v"(ta),"+v"(tb),
                       "+v"(tc),"+v"(td),"+v"(te),"+v"(tf) :: "memory");
        const bool hi = (rm & 1);
#define ACC1(d) sacc += bf2f(hi ? ((d) >> 16) : ((d) & 0xffffu))
        ACC1(t0); ACC1(t1); ACC1(t2); ACC1(t3);
        ACC1(t4); ACC1(t5); ACC1(t6); ACC1(t7);
        ACC1(t8); ACC1(t9); ACC1(ta); ACC1(tb);
        ACC1(tc); ACC1(td); ACC1(te); ACC1(tf);
#undef ACC1
    }
    const int step = s >> 2, sub = s & 3;
    if (sub == 0)
        dtv = tt[(step + 1) * Bn + brow] - tt[step * Bn + brow];
    const float kk = dtv * (sacc + b2c);
    float yin;
    if (sub == 0)      { ks = kk;         yin = ys + 0.5f * kk; }
    else if (sub == 1) { ks += 2.f * kk;  yin = ys + 0.5f * kk; }
    else if (sub == 2) { ks += 2.f * kk;  yin = ys + kk; }
    else {
        ks += kk; ys += ks * (1.f / 6.f); yin = ys;
        __builtin_nontemporal_store(ys, &out[((step + 1) * Bn + brow) * Dn + colg]);
    }
    if (s < 251) {
        const u32 my = (u32)f2bf(yin);
        const u32 pu = (u32)__shfl_xor((int)my, 16, 64);
        if ((sc & 1) == 0) {
            u32* ba = ybrC + (rm << 8) + (h << 4) + (sc >> 1);
            const u32 word = my | (pu << 16);
            asm volatile("global_store_dword %0, %1, off sc0 sc1"
                         :: "v"(ba), "v"(word) : "memory");
        }
        __syncthreads();   // drains bcast stores (and gather loads) for all threads
        if (tid == 0) agent_st(fl2C + h, (u32)(s + 1));
    }
}

// 256 WGs = 16 pairs x 16 slices; WG handles chunks c0=2p, c1=2p+1 (M=16 each).
// Weights live in VGPRs (128/lane); two-chunk interleave hides flag round-trips.
__launch_bounds__(512, 2)
__global__ void ode_v7(const float* __restrict__ y0, const float* __restrict__ tt,
                       const float* __restrict__ b1, const float* __restrict__ b2,
                       const u16* __restrict__ w1p, const u16* __restrict__ w2p,
                       float* __restrict__ out, u16* __restrict__ ybuf,
                       u16* __restrict__ kpart, u32* __restrict__ flags1,
                       u32* __restrict__ flags2) {
    __shared__ u16 lds_A0[16 * 512], lds_A1[16 * 512];   // 16KB each
    __shared__ u16 lds_H0[16 * 128], lds_H1[16 * 128];   // 4KB each
    char* A0 = (char*)lds_A0; char* A1 = (char*)lds_A1;
    char* H0 = (char*)lds_H0; char* H1 = (char*)lds_H1;

    const int tid = threadIdx.x;
    const int w = tid >> 6, lane = tid & 63, l15 = lane & 15, kg = lane >> 4;
    const int p = blockIdx.x >> 4, h = blockIdx.x & 15;
    const int c0 = p << 1, c1 = c0 + 1;

    const int sc = tid >> 4, rm = tid & 15;
    const int colg = (h << 5) + sc;
    const int brow0 = (c0 << 4) + rm, brow1 = (c1 << 4) + rm;
    const float b2c = b2[colg];
    float ys0 = y0[brow0 * Dn + colg];
    float ys1 = y0[brow1 * Dn + colg];
    __builtin_nontemporal_store(ys0, &out[brow0 * Dn + colg]);
    __builtin_nontemporal_store(ys1, &out[brow1 * Dn + colg]);
    float ks0 = 0.f, ks1 = 0.f, dt0 = 0.f, dt1 = 0.f;

    // ---- weight preload into registers ----
    s16x8 w1r[16];          // W1 ntile = h*8+w, all 16 ktiles
    #pragma unroll
    for (int kt = 0; kt < 16; ++kt)
        w1r[kt] = *(const s16x8*)&w1p[((size_t)((h << 3) + w) * 16 + kt) * 512 + (lane << 3)];
    s16x8 w2r[4][4];        // W2 ntiles w*4+c, ktiles h*4+ks
    #pragma unroll
    for (int c = 0; c < 4; ++c)
        #pragma unroll
        for (int ks2 = 0; ks2 < 4; ++ks2)
            w2r[c][ks2] = *(const s16x8*)&w2p[((size_t)((w << 2) + c) * 64 + (h << 2) + ks2) * 512 + (lane << 3)];
    const float bia = b1[(h << 7) + (w << 4) + l15];

    const u32 abase = (u32)l15 * 1024u + ((u32)kg << 4);
    const u32 aswz = ((u32)(l15 & 7)) << 4;
    const u32 hbase = (u32)l15 * 256u + ((u32)kg << 4);

    u32* ybr0 = (u32*)(ybuf + (size_t)c0 * 16 * 512);
    u32* ybr1 = (u32*)(ybuf + (size_t)c1 * 16 * 512);
    char* kp0 = (char*)kpart + (size_t)c0 * (256 * 1024);
    char* kp1 = (char*)kpart + (size_t)c1 * (256 * 1024);
    u32* fl1c0 = flags1 + (c0 << 4); u32* fl1c1 = flags1 + (c1 << 4);
    u32* fl2c0 = flags2 + (c0 << 4); u32* fl2c1 = flags2 + (c1 << 4);

    #pragma unroll 1
    for (int s = 0; s < 252; ++s) {
        // ---- S1: stage A(c0) ----
        if (s == 0) {
            stage_a0(y0, c0, A0, tid);
        } else {
            if (tid < 16) {
                while (agent_ld(fl2c0 + tid) < (u32)s) __builtin_amdgcn_s_sleep(1);
            }
            __syncthreads();
            stage_a(ybr0, A0, tid);
        }
        __syncthreads();
        // ---- S2: GEMM1(c0) ----
        gemm1(A0, H0, w1r, bia, abase, aswz, w, l15, kg);
        __syncthreads();
        // ---- S3: GEMM2+store(c0) | stageA(c1) | pub flag1(c0) ----
        if (s > 0) {
            if (tid < 16) {
                while (agent_ld(fl2c1 + tid) < (u32)s) __builtin_amdgcn_s_sleep(1);
            }
            __syncthreads();
        }
        gemm2_store(H0, kp0, w2r, hbase, aswz, w, l15, kg, h);
        if (s == 0) stage_a0(y0, c1, A1, tid);
        else        stage_a(ybr1, A1, tid);
        __syncthreads();                       // drains c0 partial stores too
        if (tid == 0) agent_st(fl1c0 + h, (u32)(s + 1));
        // ---- S4: GEMM1(c1) ----
        gemm1(A1, H1, w1r, bia, abase, aswz, w, l15, kg);
        __syncthreads();
        // ---- S5: GEMM2+store(c1), pub flag1(c1) ----
        gemm2_store(H1, kp1, w2r, hbase, aswz, w, l15, kg, h);
        __syncthreads();                       // drains c1 partial stores
        if (tid == 0) agent_st(fl1c1 + h, (u32)(s + 1));
        // ---- S6/S7: owner reduce+update+bcast, c0 then c1 ----
        owner_phase(s, ys0, ks0, dt0, brow0, kp0, ybr0, fl1c0, fl2c0,
                    tt, out, b2c, colg, sc, rm, h, tid);
        owner_phase(s, ys1, ks1, dt1, brow1, kp1, ybr1, fl1c1, fl2c1,
                    tt, out, b2c, colg, sc, rm, h, tid);
    }
}

// ---------------- fallback: round-1 kernel (32 WGs) ----------------
__launch_bounds__(512, 2)
__global__ void ode_rk4_fb(const float* __restrict__ y0, const float* __restrict__ tt,
                           const float* __restrict__ b1, const float* __restrict__ b2,
                           const u16* __restrict__ w1p, const u16* __restrict__ w2p,
                           float* __restrict__ out) {
    __shared__ u16 lds_ys[16 * Dn];
    __shared__ u16 lds_hid[16 * Hn];
    __shared__ float lds_dt[16];
    const int tid = threadIdx.x;
    const int w = tid >> 6, lane = tid & 63, l15 = lane & 15, kgrp = lane >> 4;
    const int row0 = blockIdx.x << 4;
    float yreg[4][4], ksum[4][4], kk[4][4];
    float b1v[16], b2v[4], dtv[4];
    #pragma unroll
    for (int nt = 0; nt < 16; ++nt) b1v[nt] = b1[(w << 8) + (nt << 4) + l15];
    #pragma unroll
    for (int c = 0; c < 4; ++c) b2v[c] = b2[(w << 6) + (c << 4) + l15];
    #pragma unroll
    for (int c = 0; c < 4; ++c)
        #pragma unroll
        for (int j = 0; j < 4; ++j) {
            const int rr = (kgrp << 2) + j;
            const int col = (w << 6) + (c << 4) + l15;
            const float v = y0[(row0 + rr) * Dn + col];
            yreg[c][j] = v; ksum[c][j] = 0.f; kk[c][j] = 0.f;
            out[(row0 + rr) * Dn + col] = v;
        }
    const u16* wv1 = w1p + ((w << 4) * (16 * 512)) + (lane << 3);
    const u16* wv2 = w2p + ((w << 2) * (64 * 512)) + (lane << 3);
    const int arow = l15;
    const unsigned swzA = (unsigned)((arow & 7) << 3);
    for (int step = 0; step < Tn - 1; ++step) {
        if (tid < 16)
            lds_dt[tid] = tt[(step + 1) * Bn + row0 + tid] - tt[step * Bn + row0 + tid];
        #pragma unroll 1
        for (int s = 0; s < 4; ++s) {
            const float ci = (s == 3) ? 1.0f : ((s == 0) ? 0.0f : 0.5f);
            #pragma unroll
            for (int c = 0; c < 4; ++c)
                #pragma unroll
                for (int j = 0; j < 4; ++j) {
                    const int rr = (kgrp << 2) + j;
                    const int col = (w << 6) + (c << 4) + l15;
                    lds_ys[(unsigned)((rr << 9) + col) ^ (unsigned)((rr & 7) << 3)] =
                        f2bf(yreg[c][j] + ci * kk[c][j]);
                }
            __syncthreads();
            if (s == 0) {
                #pragma unroll
                for (int j = 0; j < 4; ++j) dtv[j] = lds_dt[(kgrp << 2) + j];
            }
            f32x4 acc[16];
            #pragma unroll
            for (int nt = 0; nt < 16; ++nt)
                #pragma unroll
                for (int j = 0; j < 4; ++j) acc[nt][j] = b1v[nt];
            #pragma unroll 2
            for (int kt = 0; kt < 16; ++kt) {
                const unsigned ia = ((unsigned)((arow << 9) + (kt << 5) + (kgrp << 3))) ^ swzA;
                const s16x8 a = *(const s16x8*)&lds_ys[ia];
                #pragma unroll
                for (int nt = 0; nt < 16; ++nt) {
                    const s16x8 bfrag = *(const s16x8*)&wv1[nt * 8192 + kt * 512];
                    acc[nt] = __builtin_amdgcn_mfma_f32_16x16x32_bf16(a, bfrag, acc[nt], 0, 0, 0);
                }
            }
            #pragma unroll
            for (int nt = 0; nt < 16; ++nt)
                #pragma unroll
                for (int j = 0; j < 4; ++j) {
                    const int rr = (kgrp << 2) + j;
                    const int col = (w << 8) + (nt << 4) + l15;
                    lds_hid[(unsigned)((rr << 11) + col) ^ (unsigned)((rr & 7) << 3)] =
                        f2bf(tanh_fast(acc[nt][j]));
                }
            __syncthreads();
            f32x4 acc2[4];
            #pragma unroll
            for (int c = 0; c < 4; ++c)
                #pragma unroll
                for (int j = 0; j < 4; ++j) acc2[c][j] = 0.f;
            #pragma unroll 2
            for (int kt = 0; kt < 64; ++kt) {
                const unsigned ia = ((unsigned)((arow << 11) + (kt << 5) + (kgrp << 3))) ^ swzA;
                const s16x8 a = *(const s16x8*)&lds_hid[ia];
                #pragma unroll
                for (int c = 0; c < 4; ++c) {
                    const s16x8 bfrag = *(const s16x8*)&wv2[c * 32768 + kt * 512];
                    acc2[c] = __builtin_amdgcn_mfma_f32_16x16x32_bf16(a, bfrag, acc2[c], 0, 0, 0);
                }
            }
            const float wq = (s == 0 || s == 3) ? 1.0f : 2.0f;
            #pragma unroll
            for (int c = 0; c < 4; ++c)
                #pragma unroll
                for (int j = 0; j < 4; ++j) {
                    const float kv = dtv[j] * (acc2[c][j] + b2v[c]);
                    kk[c][j] = kv;
                    ksum[c][j] = (s == 0) ? kv : ksum[c][j] + wq * kv;
                }
        }
        #pragma unroll
        for (int c = 0; c < 4; ++c)
            #pragma unroll
            for (int j = 0; j < 4; ++j) {
                const int rr = (kgrp << 2) + j;
                const int col = (w << 6) + (c << 4) + l15;
                yreg[c][j] += ksum[c][j] * (1.0f / 6.0f);
                out[((step + 1) * Bn + row0 + rr) * Dn + col] = yreg[c][j];
            }
    }
}

extern "C" void kernel_launch(void* const* d_in, const int* in_sizes, int n_in,
                              void* d_out, int out_size, void* d_ws, size_t ws_size,
                              hipStream_t stream) {
    const float* y0 = (const float*)d_in[0];
    const float* tt = (const float*)d_in[1];
    const float* W1 = (const float*)d_in[2];
    const float* b1 = (const float*)d_in[3];
    const float* W2 = (const float*)d_in[4];
    const float* b2 = (const float*)d_in[5];
    float* out = (float*)d_out;
    char* ws = (char*)d_ws;

    const size_t sz_fl = (size_t)64 * 1024;                 // flag arrays (32 chunk lines)
    const size_t sz_w = (size_t)Dn * Hn * 2;                // 2MB each
    const size_t sz_ybuf = (size_t)32 * 16 * 512 * 2;       // 512KB
    const size_t sz_kpart = (size_t)32 * 16 * 16 * 1024;    // 8MB
    const size_t needed = 2 * sz_fl + 2 * sz_w + sz_ybuf + sz_kpart + 4096;

    u32* flags1 = (u32*)ws;
    u32* flags2 = (u32*)(ws + sz_fl);
    u16* w1p = (u16*)(ws + 2 * sz_fl);
    u16* w2p = (u16*)(ws + 2 * sz_fl + sz_w);
    u16* ybuf = (u16*)(ws + 2 * sz_fl + 2 * sz_w);
    u16* kpart = (u16*)(ws + 2 * sz_fl + 2 * sz_w + sz_ybuf);

    if (ws_size >= needed) {
        hipMemsetAsync(ws, 0, 2 * sz_fl, stream);
        pack_w<<<4096, 256, 0, stream>>>(W1, W2, w1p, w2p);
        void* args[] = {&y0, &tt, &b1, &b2, &w1p, &w2p, &out, &ybuf, &kpart, &flags1, &flags2};
        hipLaunchCooperativeKernel((void*)ode_v7, dim3(256), dim3(512), args, 0, stream);
    } else {
        u16* f1 = (u16*)ws;
        u16* f2 = f1 + (size_t)Dn * Hn;
        pack_w<<<4096, 256, 0, stream>>>(W1, W2, f1, f2);
        ode_rk4_fb<<<32, 512, 0, stream>>>(y0, tt, b1, b2, f1, f2, out);
    }
}